// Round 8
// baseline (419.358 us; speedup 1.0000x reference)
//
#include <hip/hip_runtime.h>
#include <hip/hip_bf16.h>
#include <math.h>

// OLMoE sparse MoE block: E=32, K=4, H=2048, F=1024, T=1024 tokens.
#define NE 32
#define NK 4
#define NH 2048
#define NF 1024
#define NT 1024

#define BM 128
#define BN 64
#define BK 64
#define MAXTILES 64

typedef __attribute__((ext_vector_type(8))) short short8;
typedef __attribute__((ext_vector_type(4))) float f32x4;

#define ASMV(s) asm volatile(s ::: "memory")

// Workspace layout (bytes); total ~46 MB
static constexpr size_t OFF_CNT = 0;
static constexpr size_t OFF_ENT = 1024;
static constexpr size_t OFF_WTK = 1024 + 32 * 1024 * 4;
static constexpr size_t OFF_TIL = 200704;
static constexpr size_t OFF_XB  = 262144;
static constexpr size_t OFF_ACT = OFF_XB + (size_t)NT * NH * 2;
static constexpr size_t OFF_YP  = OFF_ACT + (size_t)NT * NK * NF * 2;

// ---------------------------------------------------------------------------
__device__ inline unsigned bfbits(float f) {
  return (unsigned)__builtin_bit_cast(unsigned short, __float2bfloat16(f));
}
__device__ inline unsigned pkbf(float lo, float hi) {
  return bfbits(lo) | (bfbits(hi) << 16);
}
// XOR-swizzled element index for a [rows][64] bf16 tile (row stride 128 B).
// byte = r*128 + k*2, byte ^= (r&7)<<4. Involution, 16B-block preserving.
__device__ inline int swz(int r, int k) {
  int b = (r << 7) | (k << 1);
  return (b ^ ((r & 7) << 4)) >> 1;
}

// ---------------------------------------------------------------------------
// Kernel 1: router (unchanged, validated).
// ---------------------------------------------------------------------------
__global__ __launch_bounds__(256) void router_kernel(
    const float* __restrict__ x, const float* __restrict__ gate_w,
    float* __restrict__ logits_out, int* __restrict__ cnt,
    int* __restrict__ entries, float* __restrict__ w_tk,
    unsigned short* __restrict__ xb) {
  __shared__ float xs[NH];
  __shared__ float logits_s[NE];
  const int t = blockIdx.x;
  const int tid = threadIdx.x;

  for (int i = tid; i < NH / 4; i += 256) {
    *reinterpret_cast<float4*>(&xs[i * 4]) =
        *reinterpret_cast<const float4*>(&x[(size_t)t * NH + i * 4]);
  }
  __syncthreads();

  {
    unsigned u[4];
#pragma unroll
    for (int j = 0; j < 4; ++j)
      u[j] = pkbf(xs[tid * 8 + 2 * j], xs[tid * 8 + 2 * j + 1]);
    *reinterpret_cast<uint4*>(&xb[(size_t)t * NH + tid * 8]) =
        make_uint4(u[0], u[1], u[2], u[3]);
  }

  const int wave = tid >> 6, lane = tid & 63;
  for (int ei = 0; ei < 8; ++ei) {
    const int e = wave * 8 + ei;
    const float* gw = gate_w + (size_t)e * NH;
    float s = 0.f;
    for (int h = lane; h < NH; h += 64) s += xs[h] * gw[h];
#pragma unroll
    for (int off = 32; off >= 1; off >>= 1) s += __shfl_xor(s, off, 64);
    if (lane == 0) logits_s[e] = s;
  }
  __syncthreads();

  if (wave == 0) {
    float v = (lane < NE) ? logits_s[lane] : -INFINITY;
    if (lane < NE) logits_out[(size_t)t * NE + lane] = v;
    float m = v;
#pragma unroll
    for (int off = 32; off >= 1; off >>= 1) m = fmaxf(m, __shfl_xor(m, off, 64));
    float ex = (lane < NE) ? expf(v - m) : 0.f;
    float sum = ex;
#pragma unroll
    for (int off = 32; off >= 1; off >>= 1) sum += __shfl_xor(sum, off, 64);
    float pv = (lane < NE) ? (ex / sum) : -1.f;
    for (int k = 0; k < NK; ++k) {
      float bv = pv;
      int bi = lane;
#pragma unroll
      for (int off = 32; off >= 1; off >>= 1) {
        float ov = __shfl_xor(bv, off, 64);
        int oi = __shfl_xor(bi, off, 64);
        if (ov > bv || (ov == bv && oi < bi)) { bv = ov; bi = oi; }
      }
      if (lane == 0) {
        int pos = atomicAdd(&cnt[bi], 1);
        entries[bi * NT + pos] = t * NK + k;
        w_tk[t * NK + k] = bv;
      }
      if (lane == bi) pv = -1.f;
    }
  }
}

// ---------------------------------------------------------------------------
// Kernel 1b: compact (expert, rowtile) tile table (unchanged).
// ---------------------------------------------------------------------------
__global__ __launch_bounds__(64) void build_tiles(
    const int* __restrict__ cnt, int* __restrict__ tile_hdr) {
  const int lane = threadIdx.x;
  int c = (lane < NE) ? cnt[lane] : 0;
  int nt = (c + BM - 1) / BM;
  int pre = nt;
#pragma unroll
  for (int d = 1; d < 32; d <<= 1) {
    int v = __shfl_up(pre, d, 64);
    if (lane >= d) pre += v;
  }
  int start = pre - nt;
  if (lane < NE) {
    for (int i = 0; i < nt; ++i) tile_hdr[1 + start + i] = (lane << 4) | i;
  }
  if (lane == NE - 1) tile_hdr[0] = pre;
}

// ---------------------------------------------------------------------------
// Kernel 2: gate+up MFMA GEMM + SwiGLU. Tile 128(pairs) x 64(f), K=2048.
// 512 threads = 8 waves (4m x 2n); wave tile 32m x 32n (2mf x 2nf).
// A: bf16 xb -> registers JIT (L2-resident; compiler-counted waits).
// B: fp32 dwordx2 paired-column loads -> regs (distance 2, named slots)
//    -> bf16 -> swizzled LDS dbuf. Only manual sync: lgkmcnt(0)+s_barrier.
// grid = (NF/64=16, MAXTILES).
// ---------------------------------------------------------------------------
__global__ __launch_bounds__(512, 4) void phase1_mfma(
    const unsigned short* __restrict__ xb, const float* __restrict__ wg,
    const float* __restrict__ wu, const int* __restrict__ tile_hdr,
    const int* __restrict__ entries, const int* __restrict__ cnt,
    unsigned short* __restrict__ act) {
  const int s = blockIdx.y;
  if (s >= tile_hdr[0]) return;
  const int packed = tile_hdr[1 + s];
  const int e = packed >> 4, rt = packed & 15;
  const int n_e = cnt[e];
  const int f0 = blockIdx.x * BN;

  __shared__ unsigned short Bgs[2][BN * BK];  // 2 x 8 KB, [n][k] swizzled
  __shared__ unsigned short Bus[2][BN * BK];  // 2 x 8 KB
  __shared__ int pair_s[BM];

  const int tid = threadIdx.x;
  if (tid < BM) {
    int idx = rt * BM + tid;
    pair_s[tid] = (idx < n_e) ? entries[e * NT + idx] : -1;
  }
  __syncthreads();

  const int lane = tid & 63, wid = tid >> 6;
  const int wm = (wid >> 1) * 32, wn = (wid & 1) * 32;
  const int lm = lane & 15, lk = (lane >> 4) * 8;

  // A row pointers (2 m-frags per wave)
  const unsigned short* aptr[2];
#pragma unroll
  for (int mf = 0; mf < 2; ++mf) {
    int p = pair_s[wm + mf * 16 + lm];
    int tok = (p >= 0) ? (p >> 2) : 0;
    aptr[mf] = xb + (size_t)tok * NH + lk;
  }

  // B staging: thread covers n in {np*2, np*2+1}, k in [kq*4, kq*4+4)
  const int np = tid & 31, kq = tid >> 5;  // kq in 0..15
  const float* bgp = wg + (size_t)e * NH * NF + f0 + np * 2;
  const float* bup = wu + (size_t)e * NH * NF + f0 + np * 2;

  float2 g0[4], u0[4], g1[4], u1[4];  // two named B slots (distance 2)

  f32x4 accg[2][2], accu[2][2];
#pragma unroll
  for (int i = 0; i < 2; ++i)
#pragma unroll
    for (int j = 0; j < 2; ++j) {
      accg[i][j] = (f32x4)(0.f);
      accu[i][j] = (f32x4)(0.f);
    }

  auto loadB = [&](int k0, float2 (&g)[4], float2 (&u)[4]) {
#pragma unroll
    for (int i = 0; i < 4; ++i) {
      const size_t row = (size_t)(k0 + kq * 4 + i) * NF;
      g[i] = *reinterpret_cast<const float2*>(bgp + row);
      u[i] = *reinterpret_cast<const float2*>(bup + row);
    }
  };
  auto storeB = [&](const float2 (&g)[4], const float2 (&u)[4], int b) {
    uint2 c0, c1;
    c0.x = pkbf(g[0].x, g[1].x); c0.y = pkbf(g[2].x, g[3].x);
    c1.x = pkbf(g[0].y, g[1].y); c1.y = pkbf(g[2].y, g[3].y);
    *reinterpret_cast<uint2*>(&Bgs[b][swz(np * 2, kq * 4)]) = c0;
    *reinterpret_cast<uint2*>(&Bgs[b][swz(np * 2 + 1, kq * 4)]) = c1;
    c0.x = pkbf(u[0].x, u[1].x); c0.y = pkbf(u[2].x, u[3].x);
    c1.x = pkbf(u[0].y, u[1].y); c1.y = pkbf(u[2].y, u[3].y);
    *reinterpret_cast<uint2*>(&Bus[b][swz(np * 2, kq * 4)]) = c0;
    *reinterpret_cast<uint2*>(&Bus[b][swz(np * 2 + 1, kq * 4)]) = c1;
  };
  auto compute = [&](int c, int k0) {
    short8 a[2][2];
#pragma unroll
    for (int kc = 0; kc < 2; ++kc)
#pragma unroll
      for (int mf = 0; mf < 2; ++mf)
        a[kc][mf] = *reinterpret_cast<const short8*>(aptr[mf] + k0 + kc * 32);
#pragma unroll
    for (int kc = 0; kc < 2; ++kc) {
      short8 bg[2], bu[2];
#pragma unroll
      for (int nf = 0; nf < 2; ++nf) {
        bg[nf] = *reinterpret_cast<const short8*>(
            &Bgs[c][swz(wn + nf * 16 + lm, kc * 32 + lk)]);
        bu[nf] = *reinterpret_cast<const short8*>(
            &Bus[c][swz(wn + nf * 16 + lm, kc * 32 + lk)]);
      }
#pragma unroll
      for (int mf = 0; mf < 2; ++mf)
#pragma unroll
        for (int nf = 0; nf < 2; ++nf) {
          accg[mf][nf] = __builtin_amdgcn_mfma_f32_16x16x32_bf16(a[kc][mf], bg[nf], accg[mf][nf], 0, 0, 0);
          accu[mf][nf] = __builtin_amdgcn_mfma_f32_16x16x32_bf16(a[kc][mf], bu[nf], accu[mf][nf], 0, 0, 0);
        }
    }
  };

  const int NS = NH / BK;  // 32
  // prologue: B(0)->buf0 staged; B(1) in flight in slot1
  loadB(0, g0, u0);
  loadB(BK, g1, u1);
  storeB(g0, u0, 0);  // compiler auto-waits slot0's loads only
  ASMV("s_waitcnt lgkmcnt(0)");
  __builtin_amdgcn_s_barrier();
  __builtin_amdgcn_sched_barrier(0);

  for (int t = 0; t < NS - 2; t += 2) {
    loadB((t + 2) * BK, g0, u0);   // slot0 free (B(t) consumed)
    compute(0, t * BK);
    storeB(g1, u1, 1);             // auto-wait slot1 (B(t+1)); slot0 stays in flight
    ASMV("s_waitcnt lgkmcnt(0)");
    __builtin_amdgcn_s_barrier();
    __builtin_amdgcn_sched_barrier(0);
    loadB((t + 3) * BK, g1, u1);
    compute(1, (t + 1) * BK);
    storeB(g0, u0, 0);
    ASMV("s_waitcnt lgkmcnt(0)");
    __builtin_amdgcn_s_barrier();
    __builtin_amdgcn_sched_barrier(0);
  }
  compute(0, (NS - 2) * BK);
  storeB(g1, u1, 1);
  ASMV("s_waitcnt lgkmcnt(0)");
  __builtin_amdgcn_s_barrier();
  __builtin_amdgcn_sched_barrier(0);
  compute(1, (NS - 1) * BK);

  // epilogue: silu(g)*u -> act bf16. D layout: col=lane&15, row=(lane>>4)*4+r.
  const int rbase = wm + (lane >> 4) * 4;
#pragma unroll
  for (int mf = 0; mf < 2; ++mf) {
#pragma unroll
    for (int r = 0; r < 4; ++r) {
      const int row = rbase + mf * 16 + r;
      const int p = pair_s[row];
      if (p < 0) continue;
#pragma unroll
      for (int nf = 0; nf < 2; ++nf) {
        float g = accg[mf][nf][r], u = accu[mf][nf][r];
        float o = (g / (1.f + __expf(-g))) * u;
        act[(size_t)p * NF + f0 + wn + nf * 16 + lm] = (unsigned short)bfbits(o);
      }
    }
  }
}

// ---------------------------------------------------------------------------
// Kernel 3: down-proj MFMA GEMM, same structure. Tile 128 x 64 over H,
// K=F=1024, 512 threads. grid = (NH/64=32, MAXTILES).
// ---------------------------------------------------------------------------
__global__ __launch_bounds__(512, 4) void phase2_mfma(
    const unsigned short* __restrict__ act, const float* __restrict__ wd,
    const int* __restrict__ tile_hdr, const int* __restrict__ entries,
    const int* __restrict__ cnt, float* __restrict__ yp) {
  const int s = blockIdx.y;
  if (s >= tile_hdr[0]) return;
  const int packed = tile_hdr[1 + s];
  const int e = packed >> 4, rt = packed & 15;
  const int n_e = cnt[e];
  const int h0 = blockIdx.x * BN;

  __shared__ unsigned short Bs[2][BN * BK];  // 2 x 8 KB
  __shared__ int pair_s[BM];

  const int tid = threadIdx.x;
  if (tid < BM) {
    int idx = rt * BM + tid;
    pair_s[tid] = (idx < n_e) ? entries[e * NT + idx] : -1;
  }
  __syncthreads();

  const int lane = tid & 63, wid = tid >> 6;
  const int wm = (wid >> 1) * 32, wn = (wid & 1) * 32;
  const int lm = lane & 15, lk = (lane >> 4) * 8;

  const unsigned short* aptr[2];
#pragma unroll
  for (int mf = 0; mf < 2; ++mf) {
    int p = pair_s[wm + mf * 16 + lm];
    int pa = (p >= 0) ? p : 0;
    aptr[mf] = act + (size_t)pa * NF + lk;
  }

  const int np = tid & 31, kq = tid >> 5;
  const float* bdp = wd + (size_t)e * NF * NH + h0 + np * 2;

  float2 d0[4], d1[4];

  f32x4 acc[2][2];
#pragma unroll
  for (int i = 0; i < 2; ++i)
#pragma unroll
    for (int j = 0; j < 2; ++j) acc[i][j] = (f32x4)(0.f);

  auto loadB = [&](int k0, float2 (&d)[4]) {
#pragma unroll
    for (int i = 0; i < 4; ++i)
      d[i] = *reinterpret_cast<const float2*>(bdp + (size_t)(k0 + kq * 4 + i) * NH);
  };
  auto storeB = [&](const float2 (&d)[4], int b) {
    uint2 c0, c1;
    c0.x = pkbf(d[0].x, d[1].x); c0.y = pkbf(d[2].x, d[3].x);
    c1.x = pkbf(d[0].y, d[1].y); c1.y = pkbf(d[2].y, d[3].y);
    *reinterpret_cast<uint2*>(&Bs[b][swz(np * 2, kq * 4)]) = c0;
    *reinterpret_cast<uint2*>(&Bs[b][swz(np * 2 + 1, kq * 4)]) = c1;
  };
  auto compute = [&](int c, int k0) {
    short8 a[2][2];
#pragma unroll
    for (int kc = 0; kc < 2; ++kc)
#pragma unroll
      for (int mf = 0; mf < 2; ++mf)
        a[kc][mf] = *reinterpret_cast<const short8*>(aptr[mf] + k0 + kc * 32);
#pragma unroll
    for (int kc = 0; kc < 2; ++kc) {
      short8 b2[2];
#pragma unroll
      for (int nf = 0; nf < 2; ++nf)
        b2[nf] = *reinterpret_cast<const short8*>(
            &Bs[c][swz(wn + nf * 16 + lm, kc * 32 + lk)]);
#pragma unroll
      for (int mf = 0; mf < 2; ++mf)
#pragma unroll
        for (int nf = 0; nf < 2; ++nf)
          acc[mf][nf] = __builtin_amdgcn_mfma_f32_16x16x32_bf16(a[kc][mf], b2[nf], acc[mf][nf], 0, 0, 0);
    }
  };

  const int NS = NF / BK;  // 16
  loadB(0, d0);
  loadB(BK, d1);
  storeB(d0, 0);
  ASMV("s_waitcnt lgkmcnt(0)");
  __builtin_amdgcn_s_barrier();
  __builtin_amdgcn_sched_barrier(0);

  for (int t = 0; t < NS - 2; t += 2) {
    loadB((t + 2) * BK, d0);
    compute(0, t * BK);
    storeB(d1, 1);
    ASMV("s_waitcnt lgkmcnt(0)");
    __builtin_amdgcn_s_barrier();
    __builtin_amdgcn_sched_barrier(0);
    loadB((t + 3) * BK, d1);
    compute(1, (t + 1) * BK);
    storeB(d0, 0);
    ASMV("s_waitcnt lgkmcnt(0)");
    __builtin_amdgcn_s_barrier();
    __builtin_amdgcn_sched_barrier(0);
  }
  compute(0, (NS - 2) * BK);
  storeB(d1, 1);
  ASMV("s_waitcnt lgkmcnt(0)");
  __builtin_amdgcn_s_barrier();
  __builtin_amdgcn_sched_barrier(0);
  compute(1, (NS - 1) * BK);

  const int rbase = wm + (lane >> 4) * 4;
#pragma unroll
  for (int mf = 0; mf < 2; ++mf) {
#pragma unroll
    for (int r = 0; r < 4; ++r) {
      const int row = rbase + mf * 16 + r;
      const int p = pair_s[row];
      if (p < 0) continue;
#pragma unroll
      for (int nf = 0; nf < 2; ++nf)
        yp[(size_t)p * NH + h0 + wn + nf * 16 + lm] = acc[mf][nf][r];
    }
  }
}

// ---------------------------------------------------------------------------
// Kernel 4: combine (unchanged).
// ---------------------------------------------------------------------------
__global__ __launch_bounds__(256) void combine_kernel(
    const float* __restrict__ yp, const float* __restrict__ w_tk,
    float* __restrict__ out) {
  const size_t idx = (size_t)blockIdx.x * 256 + threadIdx.x;
  const int t = (int)(idx >> 9);
  const int h4 = (int)(idx & 511) * 4;
  float4 s = make_float4(0.f, 0.f, 0.f, 0.f);
#pragma unroll
  for (int k = 0; k < NK; ++k) {
    const float w = w_tk[t * NK + k];
    const float4 v = *reinterpret_cast<const float4*>(
        &yp[((size_t)(t * NK + k)) * NH + h4]);
    s.x += w * v.x; s.y += w * v.y; s.z += w * v.z; s.w += w * v.w;
  }
  *reinterpret_cast<float4*>(&out[(size_t)t * NH + h4]) = s;
}

// ---------------------------------------------------------------------------
extern "C" void kernel_launch(void* const* d_in, const int* in_sizes, int n_in,
                              void* d_out, int out_size, void* d_ws,
                              size_t ws_size, hipStream_t stream) {
  const float* x      = (const float*)d_in[0];
  const float* gate_w = (const float*)d_in[1];
  const float* wg     = (const float*)d_in[2];
  const float* wu     = (const float*)d_in[3];
  const float* wd     = (const float*)d_in[4];

  float* out        = (float*)d_out;
  float* logits_out = (float*)d_out + (size_t)NT * NH;

  char* ws = (char*)d_ws;
  int* cnt            = (int*)(ws + OFF_CNT);
  int* entries        = (int*)(ws + OFF_ENT);
  float* w_tk         = (float*)(ws + OFF_WTK);
  int* tile_hdr       = (int*)(ws + OFF_TIL);
  unsigned short* xb  = (unsigned short*)(ws + OFF_XB);
  unsigned short* act = (unsigned short*)(ws + OFF_ACT);
  float* yp           = (float*)(ws + OFF_YP);

  hipMemsetAsync(ws, 0, 1024, stream);  // zero expert counters

  router_kernel<<<NT, 256, 0, stream>>>(x, gate_w, logits_out, cnt, entries, w_tk, xb);
  build_tiles<<<1, 64, 0, stream>>>(cnt, tile_hdr);
  phase1_mfma<<<dim3(NF / BN, MAXTILES), 512, 0, stream>>>(xb, wg, wu, tile_hdr, entries, cnt, act);
  phase2_mfma<<<dim3(NH / BN, MAXTILES), 512, 0, stream>>>(act, wd, tile_hdr, entries, cnt, yp);
  combine_kernel<<<(NT * NH / 4) / 256, 256, 0, stream>>>(yp, w_tk, out);
}

// Round 9
// 387.836 us; speedup vs baseline: 1.0813x; 1.0813x over previous
//
#include <hip/hip_runtime.h>
#include <hip/hip_bf16.h>
#include <math.h>

// OLMoE sparse MoE block: E=32, K=4, H=2048, F=1024, T=1024 tokens.
#define NE 32
#define NK 4
#define NH 2048
#define NF 1024
#define NT 1024

#define BM 128
#define BN 64
#define BK 64
#define MAXTILES 64

typedef __attribute__((ext_vector_type(8))) short short8;
typedef __attribute__((ext_vector_type(4))) float f32x4;

#define ASMV(s) asm volatile(s ::: "memory")

// Workspace layout (bytes); total ~46 MB
static constexpr size_t OFF_CNT = 0;
static constexpr size_t OFF_ENT = 1024;
static constexpr size_t OFF_WTK = 1024 + 32 * 1024 * 4;
static constexpr size_t OFF_TIL = 200704;
static constexpr size_t OFF_XB  = 262144;
static constexpr size_t OFF_ACT = OFF_XB + (size_t)NT * NH * 2;
static constexpr size_t OFF_YP  = OFF_ACT + (size_t)NT * NK * NF * 2;

// ---------------------------------------------------------------------------
__device__ inline unsigned bfbits(float f) {
  return (unsigned)__builtin_bit_cast(unsigned short, __float2bfloat16(f));
}
__device__ inline unsigned pkbf(float lo, float hi) {
  return bfbits(lo) | (bfbits(hi) << 16);
}
// XOR-swizzled element index for a [rows][64] bf16 tile (row stride 128 B).
__device__ inline int swz(int r, int k) {
  int b = (r << 7) | (k << 1);
  return (b ^ ((r & 7) << 4)) >> 1;
}

// ---------------------------------------------------------------------------
// Kernel 1: router (unchanged, validated).
// ---------------------------------------------------------------------------
__global__ __launch_bounds__(256) void router_kernel(
    const float* __restrict__ x, const float* __restrict__ gate_w,
    float* __restrict__ logits_out, int* __restrict__ cnt,
    int* __restrict__ entries, float* __restrict__ w_tk,
    unsigned short* __restrict__ xb) {
  __shared__ float xs[NH];
  __shared__ float logits_s[NE];
  const int t = blockIdx.x;
  const int tid = threadIdx.x;

  for (int i = tid; i < NH / 4; i += 256) {
    *reinterpret_cast<float4*>(&xs[i * 4]) =
        *reinterpret_cast<const float4*>(&x[(size_t)t * NH + i * 4]);
  }
  __syncthreads();

  {
    unsigned u[4];
#pragma unroll
    for (int j = 0; j < 4; ++j)
      u[j] = pkbf(xs[tid * 8 + 2 * j], xs[tid * 8 + 2 * j + 1]);
    *reinterpret_cast<uint4*>(&xb[(size_t)t * NH + tid * 8]) =
        make_uint4(u[0], u[1], u[2], u[3]);
  }

  const int wave = tid >> 6, lane = tid & 63;
  for (int ei = 0; ei < 8; ++ei) {
    const int e = wave * 8 + ei;
    const float* gw = gate_w + (size_t)e * NH;
    float s = 0.f;
    for (int h = lane; h < NH; h += 64) s += xs[h] * gw[h];
#pragma unroll
    for (int off = 32; off >= 1; off >>= 1) s += __shfl_xor(s, off, 64);
    if (lane == 0) logits_s[e] = s;
  }
  __syncthreads();

  if (wave == 0) {
    float v = (lane < NE) ? logits_s[lane] : -INFINITY;
    if (lane < NE) logits_out[(size_t)t * NE + lane] = v;
    float m = v;
#pragma unroll
    for (int off = 32; off >= 1; off >>= 1) m = fmaxf(m, __shfl_xor(m, off, 64));
    float ex = (lane < NE) ? expf(v - m) : 0.f;
    float sum = ex;
#pragma unroll
    for (int off = 32; off >= 1; off >>= 1) sum += __shfl_xor(sum, off, 64);
    float pv = (lane < NE) ? (ex / sum) : -1.f;
    for (int k = 0; k < NK; ++k) {
      float bv = pv;
      int bi = lane;
#pragma unroll
      for (int off = 32; off >= 1; off >>= 1) {
        float ov = __shfl_xor(bv, off, 64);
        int oi = __shfl_xor(bi, off, 64);
        if (ov > bv || (ov == bv && oi < bi)) { bv = ov; bi = oi; }
      }
      if (lane == 0) {
        int pos = atomicAdd(&cnt[bi], 1);
        entries[bi * NT + pos] = t * NK + k;
        w_tk[t * NK + k] = bv;
      }
      if (lane == bi) pv = -1.f;
    }
  }
}

// ---------------------------------------------------------------------------
// Kernel 1b: compact (expert, rowtile) tile table (unchanged).
// ---------------------------------------------------------------------------
__global__ __launch_bounds__(64) void build_tiles(
    const int* __restrict__ cnt, int* __restrict__ tile_hdr) {
  const int lane = threadIdx.x;
  int c = (lane < NE) ? cnt[lane] : 0;
  int nt = (c + BM - 1) / BM;
  int pre = nt;
#pragma unroll
  for (int d = 1; d < 32; d <<= 1) {
    int v = __shfl_up(pre, d, 64);
    if (lane >= d) pre += v;
  }
  int start = pre - nt;
  if (lane < NE) {
    for (int i = 0; i < nt; ++i) tile_hdr[1 + start + i] = (lane << 4) | i;
  }
  if (lane == NE - 1) tile_hdr[0] = pre;
}

// ---------------------------------------------------------------------------
// Kernel 2: gate+up MFMA GEMM + SwiGLU. Tile 128(pairs) x 64(f), K=2048.
// 512 threads = 8 waves (4m x 2n); wave tile 32m x 32n.
// B: fp32 -> regs (distance 2, named slots, sched_barrier-pinned) -> bf16
//    -> swizzled LDS dbuf. A: bf16 regs, distance 1 (named cur/next).
// grid = (NF/64=16, MAXTILES).
// ---------------------------------------------------------------------------
__global__ __launch_bounds__(512) void phase1_mfma(
    const unsigned short* __restrict__ xb, const float* __restrict__ wg,
    const float* __restrict__ wu, const int* __restrict__ tile_hdr,
    const int* __restrict__ entries, const int* __restrict__ cnt,
    unsigned short* __restrict__ act) {
  const int s = blockIdx.y;
  if (s >= tile_hdr[0]) return;
  const int packed = tile_hdr[1 + s];
  const int e = packed >> 4, rt = packed & 15;
  const int n_e = cnt[e];
  const int f0 = blockIdx.x * BN;

  __shared__ unsigned short Bgs[2][BN * BK];  // 2 x 8 KB, [n][k] swizzled
  __shared__ unsigned short Bus[2][BN * BK];  // 2 x 8 KB
  __shared__ int pair_s[BM];

  const int tid = threadIdx.x;
  if (tid < BM) {
    int idx = rt * BM + tid;
    pair_s[tid] = (idx < n_e) ? entries[e * NT + idx] : -1;
  }
  __syncthreads();

  const int lane = tid & 63, wid = tid >> 6;
  const int wm = (wid >> 1) * 32, wn = (wid & 1) * 32;
  const int lm = lane & 15, lk = (lane >> 4) * 8;

  // A row pointers (2 m-frags per wave)
  const unsigned short* aptr[2];
#pragma unroll
  for (int mf = 0; mf < 2; ++mf) {
    int p = pair_s[wm + mf * 16 + lm];
    int tok = (p >= 0) ? (p >> 2) : 0;
    aptr[mf] = xb + (size_t)tok * NH + lk;
  }

  // B staging roles: column bn = tid&63, k-eighth kq = tid>>6 (8 k each)
  const int bn = tid & 63, kq = tid >> 6;
  const float* bgp = wg + (size_t)e * NH * NF + f0 + bn;
  const float* bup = wu + (size_t)e * NH * NF + f0 + bn;

  float g0[8], u0[8], g1[8], u1[8];   // two named B slots (distance 2)
  short8 aA[2][2], aB[2][2];          // A cur/next (distance 1)

  f32x4 accg[2][2], accu[2][2];
#pragma unroll
  for (int i = 0; i < 2; ++i)
#pragma unroll
    for (int j = 0; j < 2; ++j) {
      accg[i][j] = (f32x4)(0.f);
      accu[i][j] = (f32x4)(0.f);
    }

  auto loadB = [&](int k0, float (&g)[8], float (&u)[8]) {
#pragma unroll
    for (int i = 0; i < 8; ++i) {
      const size_t row = (size_t)(k0 + kq * 8 + i) * NF;
      g[i] = bgp[row];
      u[i] = bup[row];
    }
  };
  auto storeB = [&](const float (&g)[8], const float (&u)[8], int b) {
    uint2 c0;
    c0.x = pkbf(g[0], g[1]); c0.y = pkbf(g[2], g[3]);
    *reinterpret_cast<uint2*>(&Bgs[b][swz(bn, kq * 8)]) = c0;
    c0.x = pkbf(g[4], g[5]); c0.y = pkbf(g[6], g[7]);
    *reinterpret_cast<uint2*>(&Bgs[b][swz(bn, kq * 8 + 4)]) = c0;
    c0.x = pkbf(u[0], u[1]); c0.y = pkbf(u[2], u[3]);
    *reinterpret_cast<uint2*>(&Bus[b][swz(bn, kq * 8)]) = c0;
    c0.x = pkbf(u[4], u[5]); c0.y = pkbf(u[6], u[7]);
    *reinterpret_cast<uint2*>(&Bus[b][swz(bn, kq * 8 + 4)]) = c0;
  };
  auto loadA = [&](int k0, short8 (&a)[2][2]) {
#pragma unroll
    for (int kc = 0; kc < 2; ++kc)
#pragma unroll
      for (int mf = 0; mf < 2; ++mf)
        a[kc][mf] = *reinterpret_cast<const short8*>(aptr[mf] + k0 + kc * 32);
  };
  auto compute = [&](int c, const short8 (&a)[2][2]) {
#pragma unroll
    for (int kc = 0; kc < 2; ++kc) {
      short8 bg[2], bu[2];
#pragma unroll
      for (int nf = 0; nf < 2; ++nf) {
        bg[nf] = *reinterpret_cast<const short8*>(
            &Bgs[c][swz(wn + nf * 16 + lm, kc * 32 + lk)]);
        bu[nf] = *reinterpret_cast<const short8*>(
            &Bus[c][swz(wn + nf * 16 + lm, kc * 32 + lk)]);
      }
#pragma unroll
      for (int mf = 0; mf < 2; ++mf)
#pragma unroll
        for (int nf = 0; nf < 2; ++nf) {
          accg[mf][nf] = __builtin_amdgcn_mfma_f32_16x16x32_bf16(a[kc][mf], bg[nf], accg[mf][nf], 0, 0, 0);
          accu[mf][nf] = __builtin_amdgcn_mfma_f32_16x16x32_bf16(a[kc][mf], bu[nf], accu[mf][nf], 0, 0, 0);
        }
    }
  };

  const int NS = NH / BK;  // 32
  // prologue: B(0)->buf0 staged; B(1) in flight in slot1; A(0) in regs
  loadB(0, g0, u0);
  loadB(BK, g1, u1);
  loadA(0, aA);
  storeB(g0, u0, 0);  // compiler auto-waits slot0's loads only
  ASMV("s_waitcnt lgkmcnt(0)");
  __builtin_amdgcn_s_barrier();
  __builtin_amdgcn_sched_barrier(0);

  for (int t = 0; t < NS - 2; t += 2) {
    // even: compute tile t from buf0 with aA
    loadB((t + 2) * BK, g0, u0);       // slot0 free (B(t) consumed)
    loadA((t + 1) * BK, aB);
    __builtin_amdgcn_sched_barrier(0); // pin prefetch issue before compute
    compute(0, aA);
    storeB(g1, u1, 1);                 // B(t+1) -> buf1 (auto-wait slot1)
    ASMV("s_waitcnt lgkmcnt(0)");
    __builtin_amdgcn_s_barrier();
    __builtin_amdgcn_sched_barrier(0);
    // odd: compute tile t+1 from buf1 with aB
    loadB((t + 3) * BK, g1, u1);
    loadA((t + 2) * BK, aA);
    __builtin_amdgcn_sched_barrier(0);
    compute(1, aB);
    storeB(g0, u0, 0);                 // B(t+2) -> buf0
    ASMV("s_waitcnt lgkmcnt(0)");
    __builtin_amdgcn_s_barrier();
    __builtin_amdgcn_sched_barrier(0);
  }
  // tail: tiles NS-2 (buf0, aA) and NS-1 (buf1, aB)
  loadA((NS - 1) * BK, aB);
  __builtin_amdgcn_sched_barrier(0);
  compute(0, aA);
  storeB(g1, u1, 1);                   // B(NS-1) -> buf1
  ASMV("s_waitcnt lgkmcnt(0)");
  __builtin_amdgcn_s_barrier();
  __builtin_amdgcn_sched_barrier(0);
  compute(1, aB);

  // epilogue: silu(g)*u -> act bf16. D layout: col=lane&15, row=(lane>>4)*4+r.
  const int rbase = wm + (lane >> 4) * 4;
#pragma unroll
  for (int mf = 0; mf < 2; ++mf) {
#pragma unroll
    for (int r = 0; r < 4; ++r) {
      const int row = rbase + mf * 16 + r;
      const int p = pair_s[row];
      if (p < 0) continue;
#pragma unroll
      for (int nf = 0; nf < 2; ++nf) {
        float g = accg[mf][nf][r], u = accu[mf][nf][r];
        float o = (g / (1.f + __expf(-g))) * u;
        act[(size_t)p * NF + f0 + wn + nf * 16 + lm] = (unsigned short)bfbits(o);
      }
    }
  }
}

// ---------------------------------------------------------------------------
// Kernel 3: down-proj MFMA GEMM, same structure. Tile 128 x 64 over H,
// K=F=1024, 512 threads. grid = (NH/64=32, MAXTILES).
// ---------------------------------------------------------------------------
__global__ __launch_bounds__(512) void phase2_mfma(
    const unsigned short* __restrict__ act, const float* __restrict__ wd,
    const int* __restrict__ tile_hdr, const int* __restrict__ entries,
    const int* __restrict__ cnt, float* __restrict__ yp) {
  const int s = blockIdx.y;
  if (s >= tile_hdr[0]) return;
  const int packed = tile_hdr[1 + s];
  const int e = packed >> 4, rt = packed & 15;
  const int n_e = cnt[e];
  const int h0 = blockIdx.x * BN;

  __shared__ unsigned short Bs[2][BN * BK];  // 2 x 8 KB
  __shared__ int pair_s[BM];

  const int tid = threadIdx.x;
  if (tid < BM) {
    int idx = rt * BM + tid;
    pair_s[tid] = (idx < n_e) ? entries[e * NT + idx] : -1;
  }
  __syncthreads();

  const int lane = tid & 63, wid = tid >> 6;
  const int wm = (wid >> 1) * 32, wn = (wid & 1) * 32;
  const int lm = lane & 15, lk = (lane >> 4) * 8;

  const unsigned short* aptr[2];
#pragma unroll
  for (int mf = 0; mf < 2; ++mf) {
    int p = pair_s[wm + mf * 16 + lm];
    int pa = (p >= 0) ? p : 0;
    aptr[mf] = act + (size_t)pa * NF + lk;
  }

  const int bn = tid & 63, kq = tid >> 6;
  const float* bdp = wd + (size_t)e * NF * NH + h0 + bn;

  float d0[8], d1[8];
  short8 aA[2][2], aB[2][2];

  f32x4 acc[2][2];
#pragma unroll
  for (int i = 0; i < 2; ++i)
#pragma unroll
    for (int j = 0; j < 2; ++j) acc[i][j] = (f32x4)(0.f);

  auto loadB = [&](int k0, float (&d)[8]) {
#pragma unroll
    for (int i = 0; i < 8; ++i)
      d[i] = bdp[(size_t)(k0 + kq * 8 + i) * NH];
  };
  auto storeB = [&](const float (&d)[8], int b) {
    uint2 c0;
    c0.x = pkbf(d[0], d[1]); c0.y = pkbf(d[2], d[3]);
    *reinterpret_cast<uint2*>(&Bs[b][swz(bn, kq * 8)]) = c0;
    c0.x = pkbf(d[4], d[5]); c0.y = pkbf(d[6], d[7]);
    *reinterpret_cast<uint2*>(&Bs[b][swz(bn, kq * 8 + 4)]) = c0;
  };
  auto loadA = [&](int k0, short8 (&a)[2][2]) {
#pragma unroll
    for (int kc = 0; kc < 2; ++kc)
#pragma unroll
      for (int mf = 0; mf < 2; ++mf)
        a[kc][mf] = *reinterpret_cast<const short8*>(aptr[mf] + k0 + kc * 32);
  };
  auto compute = [&](int c, const short8 (&a)[2][2]) {
#pragma unroll
    for (int kc = 0; kc < 2; ++kc) {
      short8 b2[2];
#pragma unroll
      for (int nf = 0; nf < 2; ++nf)
        b2[nf] = *reinterpret_cast<const short8*>(
            &Bs[c][swz(wn + nf * 16 + lm, kc * 32 + lk)]);
#pragma unroll
      for (int mf = 0; mf < 2; ++mf)
#pragma unroll
        for (int nf = 0; nf < 2; ++nf)
          acc[mf][nf] = __builtin_amdgcn_mfma_f32_16x16x32_bf16(a[kc][mf], b2[nf], acc[mf][nf], 0, 0, 0);
    }
  };

  const int NS = NF / BK;  // 16
  loadB(0, d0);
  loadB(BK, d1);
  loadA(0, aA);
  storeB(d0, 0);
  ASMV("s_waitcnt lgkmcnt(0)");
  __builtin_amdgcn_s_barrier();
  __builtin_amdgcn_sched_barrier(0);

  for (int t = 0; t < NS - 2; t += 2) {
    loadB((t + 2) * BK, d0);
    loadA((t + 1) * BK, aB);
    __builtin_amdgcn_sched_barrier(0);
    compute(0, aA);
    storeB(d1, 1);
    ASMV("s_waitcnt lgkmcnt(0)");
    __builtin_amdgcn_s_barrier();
    __builtin_amdgcn_sched_barrier(0);
    loadB((t + 3) * BK, d1);
    loadA((t + 2) * BK, aA);
    __builtin_amdgcn_sched_barrier(0);
    compute(1, aB);
    storeB(d0, 0);
    ASMV("s_waitcnt lgkmcnt(0)");
    __builtin_amdgcn_s_barrier();
    __builtin_amdgcn_sched_barrier(0);
  }
  loadA((NS - 1) * BK, aB);
  __builtin_amdgcn_sched_barrier(0);
  compute(0, aA);
  storeB(d1, 1);
  ASMV("s_waitcnt lgkmcnt(0)");
  __builtin_amdgcn_s_barrier();
  __builtin_amdgcn_sched_barrier(0);
  compute(1, aB);

  const int rbase = wm + (lane >> 4) * 4;
#pragma unroll
  for (int mf = 0; mf < 2; ++mf) {
#pragma unroll
    for (int r = 0; r < 4; ++r) {
      const int row = rbase + mf * 16 + r;
      const int p = pair_s[row];
      if (p < 0) continue;
#pragma unroll
      for (int nf = 0; nf < 2; ++nf)
        yp[(size_t)p * NH + h0 + wn + nf * 16 + lm] = acc[mf][nf][r];
    }
  }
}

// ---------------------------------------------------------------------------
// Kernel 4: combine (unchanged).
// ---------------------------------------------------------------------------
__global__ __launch_bounds__(256) void combine_kernel(
    const float* __restrict__ yp, const float* __restrict__ w_tk,
    float* __restrict__ out) {
  const size_t idx = (size_t)blockIdx.x * 256 + threadIdx.x;
  const int t = (int)(idx >> 9);
  const int h4 = (int)(idx & 511) * 4;
  float4 s = make_float4(0.f, 0.f, 0.f, 0.f);
#pragma unroll
  for (int k = 0; k < NK; ++k) {
    const float w = w_tk[t * NK + k];
    const float4 v = *reinterpret_cast<const float4*>(
        &yp[((size_t)(t * NK + k)) * NH + h4]);
    s.x += w * v.x; s.y += w * v.y; s.z += w * v.z; s.w += w * v.w;
  }
  *reinterpret_cast<float4*>(&out[(size_t)t * NH + h4]) = s;
}

// ---------------------------------------------------------------------------
extern "C" void kernel_launch(void* const* d_in, const int* in_sizes, int n_in,
                              void* d_out, int out_size, void* d_ws,
                              size_t ws_size, hipStream_t stream) {
  const float* x      = (const float*)d_in[0];
  const float* gate_w = (const float*)d_in[1];
  const float* wg     = (const float*)d_in[2];
  const float* wu     = (const float*)d_in[3];
  const float* wd     = (const float*)d_in[4];

  float* out        = (float*)d_out;
  float* logits_out = (float*)d_out + (size_t)NT * NH;

  char* ws = (char*)d_ws;
  int* cnt            = (int*)(ws + OFF_CNT);
  int* entries        = (int*)(ws + OFF_ENT);
  float* w_tk         = (float*)(ws + OFF_WTK);
  int* tile_hdr       = (int*)(ws + OFF_TIL);
  unsigned short* xb  = (unsigned short*)(ws + OFF_XB);
  unsigned short* act = (unsigned short*)(ws + OFF_ACT);
  float* yp           = (float*)(ws + OFF_YP);

  hipMemsetAsync(ws, 0, 1024, stream);  // zero expert counters

  router_kernel<<<NT, 256, 0, stream>>>(x, gate_w, logits_out, cnt, entries, w_tk, xb);
  build_tiles<<<1, 64, 0, stream>>>(cnt, tile_hdr);
  phase1_mfma<<<dim3(NF / BN, MAXTILES), 512, 0, stream>>>(xb, wg, wu, tile_hdr, entries, cnt, act);
  phase2_mfma<<<dim3(NH / BN, MAXTILES), 512, 0, stream>>>(act, wd, tile_hdr, entries, cnt, yp);
  combine_kernel<<<(NT * NH / 4) / 256, 256, 0, stream>>>(yp, w_tk, out);
}

// Round 10
// 343.026 us; speedup vs baseline: 1.2225x; 1.1306x over previous
//
#include <hip/hip_runtime.h>
#include <hip/hip_bf16.h>
#include <math.h>

// OLMoE sparse MoE block: E=32, K=4, H=2048, F=1024, T=1024 tokens.
#define NE 32
#define NK 4
#define NH 2048
#define NF 1024
#define NT 1024

#define BM 192      // pairs per tile: 1 tile/expert for n_e <= 192 (typ. ~128)
#define BN 128      // output cols per block: 512 B contiguous per weight row
#define BK 64
#define MAXTILES 64

typedef __attribute__((ext_vector_type(8))) short short8;
typedef __attribute__((ext_vector_type(4))) float f32x4;

#define ASMV(s) asm volatile(s ::: "memory")

// Workspace layout (bytes); total ~46 MB
static constexpr size_t OFF_CNT = 0;
static constexpr size_t OFF_ENT = 1024;
static constexpr size_t OFF_WTK = 1024 + 32 * 1024 * 4;
static constexpr size_t OFF_TIL = 200704;
static constexpr size_t OFF_XB  = 262144;
static constexpr size_t OFF_ACT = OFF_XB + (size_t)NT * NH * 2;
static constexpr size_t OFF_YP  = OFF_ACT + (size_t)NT * NK * NF * 2;

// ---------------------------------------------------------------------------
__device__ inline unsigned bfbits(float f) {
  return (unsigned)__builtin_bit_cast(unsigned short, __float2bfloat16(f));
}
__device__ inline unsigned pkbf(float lo, float hi) {
  return bfbits(lo) | (bfbits(hi) << 16);
}
// XOR-swizzled element index for a [rows][64] bf16 tile (row stride 128 B).
// XOR key (n&7)^((n>>2)&7): reads (16 consecutive n) stay ~2-way; writes
// (n = 4q+j, fixed j across lanes) spread over 8 16B slots via q.
__device__ inline int swz(int r, int k) {
  int key = ((r & 7) ^ ((r >> 2) & 7)) & 7;
  int b = (r << 7) | (k << 1);
  return (b ^ (key << 4)) >> 1;
}

// ---------------------------------------------------------------------------
// Kernel 1: router (unchanged, validated).
// ---------------------------------------------------------------------------
__global__ __launch_bounds__(256) void router_kernel(
    const float* __restrict__ x, const float* __restrict__ gate_w,
    float* __restrict__ logits_out, int* __restrict__ cnt,
    int* __restrict__ entries, float* __restrict__ w_tk,
    unsigned short* __restrict__ xb) {
  __shared__ float xs[NH];
  __shared__ float logits_s[NE];
  const int t = blockIdx.x;
  const int tid = threadIdx.x;

  for (int i = tid; i < NH / 4; i += 256) {
    *reinterpret_cast<float4*>(&xs[i * 4]) =
        *reinterpret_cast<const float4*>(&x[(size_t)t * NH + i * 4]);
  }
  __syncthreads();

  {
    unsigned u[4];
#pragma unroll
    for (int j = 0; j < 4; ++j)
      u[j] = pkbf(xs[tid * 8 + 2 * j], xs[tid * 8 + 2 * j + 1]);
    *reinterpret_cast<uint4*>(&xb[(size_t)t * NH + tid * 8]) =
        make_uint4(u[0], u[1], u[2], u[3]);
  }

  const int wave = tid >> 6, lane = tid & 63;
  for (int ei = 0; ei < 8; ++ei) {
    const int e = wave * 8 + ei;
    const float* gw = gate_w + (size_t)e * NH;
    float s = 0.f;
    for (int h = lane; h < NH; h += 64) s += xs[h] * gw[h];
#pragma unroll
    for (int off = 32; off >= 1; off >>= 1) s += __shfl_xor(s, off, 64);
    if (lane == 0) logits_s[e] = s;
  }
  __syncthreads();

  if (wave == 0) {
    float v = (lane < NE) ? logits_s[lane] : -INFINITY;
    if (lane < NE) logits_out[(size_t)t * NE + lane] = v;
    float m = v;
#pragma unroll
    for (int off = 32; off >= 1; off >>= 1) m = fmaxf(m, __shfl_xor(m, off, 64));
    float ex = (lane < NE) ? expf(v - m) : 0.f;
    float sum = ex;
#pragma unroll
    for (int off = 32; off >= 1; off >>= 1) sum += __shfl_xor(sum, off, 64);
    float pv = (lane < NE) ? (ex / sum) : -1.f;
    for (int k = 0; k < NK; ++k) {
      float bv = pv;
      int bi = lane;
#pragma unroll
      for (int off = 32; off >= 1; off >>= 1) {
        float ov = __shfl_xor(bv, off, 64);
        int oi = __shfl_xor(bi, off, 64);
        if (ov > bv || (ov == bv && oi < bi)) { bv = ov; bi = oi; }
      }
      if (lane == 0) {
        int pos = atomicAdd(&cnt[bi], 1);
        entries[bi * NT + pos] = t * NK + k;
        w_tk[t * NK + k] = bv;
      }
      if (lane == bi) pv = -1.f;
    }
  }
}

// ---------------------------------------------------------------------------
// Kernel 1b: compact (expert, rowtile) tile table.
// ---------------------------------------------------------------------------
__global__ __launch_bounds__(64) void build_tiles(
    const int* __restrict__ cnt, int* __restrict__ tile_hdr) {
  const int lane = threadIdx.x;
  int c = (lane < NE) ? cnt[lane] : 0;
  int nt = (c + BM - 1) / BM;
  int pre = nt;
#pragma unroll
  for (int d = 1; d < 32; d <<= 1) {
    int v = __shfl_up(pre, d, 64);
    if (lane >= d) pre += v;
  }
  int start = pre - nt;
  if (lane < NE) {
    for (int i = 0; i < nt; ++i) tile_hdr[1 + start + i] = (lane << 4) | i;
  }
  if (lane == NE - 1) tile_hdr[0] = pre;
}

// ---------------------------------------------------------------------------
// Kernel 2: gate+up MFMA GEMM + SwiGLU. Tile 192(pairs) x 128(f), K=2048.
// 512 threads = 8 waves (4m x 2n); wave tile 48m x 64n (3mf x 4nf).
// B: dwordx4 f-contiguous loads (512 B/row/wave-inst) -> regs -> bf16
//    -> swizzled LDS dbuf. A: bf16 regs from L2-resident xb, issued first.
// One lgkmcnt(0)+s_barrier per K-step. grid = (NF/128=8, MAXTILES).
// ---------------------------------------------------------------------------
__global__ __launch_bounds__(512) void phase1_mfma(
    const unsigned short* __restrict__ xb, const float* __restrict__ wg,
    const float* __restrict__ wu, const int* __restrict__ tile_hdr,
    const int* __restrict__ entries, const int* __restrict__ cnt,
    unsigned short* __restrict__ act) {
  const int s = blockIdx.y;
  if (s >= tile_hdr[0]) return;
  const int packed = tile_hdr[1 + s];
  const int e = packed >> 4, rt = packed & 15;
  const int n_e = cnt[e];
  const int f0 = blockIdx.x * BN;

  __shared__ unsigned short Bgs[2][BN * BK];  // 2 x 16 KB, [n][k] swizzled
  __shared__ unsigned short Bus[2][BN * BK];  // 2 x 16 KB
  __shared__ int pair_s[BM];

  const int tid = threadIdx.x;
  if (tid < BM) {
    int idx = rt * BM + tid;
    pair_s[tid] = (idx < n_e) ? entries[e * NT + idx] : -1;
  }
  __syncthreads();

  const int lane = tid & 63, wid = tid >> 6;
  const int wm = (wid >> 1) * 48, wn = (wid & 1) * 64;
  const int lm = lane & 15, lk = (lane >> 4) * 8;

  // A row pointers (3 m-frags per wave)
  const unsigned short* aptr[3];
#pragma unroll
  for (int mf = 0; mf < 3; ++mf) {
    int p = pair_s[wm + mf * 16 + lm];
    int tok = (p >= 0) ? (p >> 2) : 0;
    aptr[mf] = xb + (size_t)tok * NH + lk;
  }

  // B staging roles: f-quad q = tid&31 (n = 4q..4q+3), k-quad g = tid>>5.
  const int q = tid & 31, g4 = (tid >> 5) * 4;
  const float* bgp = wg + (size_t)e * NH * NF + f0 + q * 4;
  const float* bup = wu + (size_t)e * NH * NF + f0 + q * 4;

  float rg[4][4], ru[4][4];  // [k-sub][f-sub]
  short8 a[3][2];            // A frags, current iter

  f32x4 accg[3][4], accu[3][4];
#pragma unroll
  for (int i = 0; i < 3; ++i)
#pragma unroll
    for (int j = 0; j < 4; ++j) {
      accg[i][j] = (f32x4)(0.f);
      accu[i][j] = (f32x4)(0.f);
    }

  auto loadA = [&](int k0) {
#pragma unroll
    for (int mf = 0; mf < 3; ++mf)
#pragma unroll
      for (int kc = 0; kc < 2; ++kc)
        a[mf][kc] = *reinterpret_cast<const short8*>(aptr[mf] + k0 + kc * 32);
  };
  auto loadB = [&](int k0) {
#pragma unroll
    for (int i = 0; i < 4; ++i) {
      const size_t off = (size_t)(k0 + g4 + i) * NF;
      float4 vg = *reinterpret_cast<const float4*>(bgp + off);
      float4 vu = *reinterpret_cast<const float4*>(bup + off);
      rg[i][0] = vg.x; rg[i][1] = vg.y; rg[i][2] = vg.z; rg[i][3] = vg.w;
      ru[i][0] = vu.x; ru[i][1] = vu.y; ru[i][2] = vu.z; ru[i][3] = vu.w;
    }
  };
  auto storeB = [&](int b) {
#pragma unroll
    for (int j = 0; j < 4; ++j) {
      const int n = q * 4 + j;
      uint2 cg, cu;
      cg.x = pkbf(rg[0][j], rg[1][j]); cg.y = pkbf(rg[2][j], rg[3][j]);
      cu.x = pkbf(ru[0][j], ru[1][j]); cu.y = pkbf(ru[2][j], ru[3][j]);
      *reinterpret_cast<uint2*>(&Bgs[b][swz(n, g4)]) = cg;
      *reinterpret_cast<uint2*>(&Bus[b][swz(n, g4)]) = cu;
    }
  };
  auto compute = [&](int c) {
#pragma unroll
    for (int kc = 0; kc < 2; ++kc) {
      short8 bg[4], bu[4];
#pragma unroll
      for (int nf = 0; nf < 4; ++nf) {
        bg[nf] = *reinterpret_cast<const short8*>(
            &Bgs[c][swz(wn + nf * 16 + lm, kc * 32 + lk)]);
        bu[nf] = *reinterpret_cast<const short8*>(
            &Bus[c][swz(wn + nf * 16 + lm, kc * 32 + lk)]);
      }
#pragma unroll
      for (int mf = 0; mf < 3; ++mf)
#pragma unroll
        for (int nf = 0; nf < 4; ++nf) {
          accg[mf][nf] = __builtin_amdgcn_mfma_f32_16x16x32_bf16(a[mf][kc], bg[nf], accg[mf][nf], 0, 0, 0);
          accu[mf][nf] = __builtin_amdgcn_mfma_f32_16x16x32_bf16(a[mf][kc], bu[nf], accu[mf][nf], 0, 0, 0);
        }
    }
  };

  const int NS = NH / BK;  // 32
  // prologue: stage B(0) into buf0
  loadB(0);
  storeB(0);
  ASMV("s_waitcnt lgkmcnt(0)");
  __builtin_amdgcn_s_barrier();
  __builtin_amdgcn_sched_barrier(0);

  for (int t = 0; t < NS; ++t) {
    const int c = t & 1;
    loadA(t * BK);                      // A first: waiting A leaves B in flight
    if (t + 1 < NS) loadB((t + 1) * BK);  // B(t+1) in flight across compute
    compute(c);
    if (t + 1 < NS) {
      storeB(c ^ 1);                    // waits only the B regs (vmcnt auto)
      ASMV("s_waitcnt lgkmcnt(0)");
      __builtin_amdgcn_s_barrier();
      __builtin_amdgcn_sched_barrier(0);
    }
  }

  // epilogue: silu(g)*u -> act bf16. D layout: col=lane&15, row=(lane>>4)*4+r.
  const int rbase = wm + (lane >> 4) * 4;
#pragma unroll
  for (int mf = 0; mf < 3; ++mf) {
#pragma unroll
    for (int r = 0; r < 4; ++r) {
      const int row = rbase + mf * 16 + r;
      const int p = pair_s[row];
      if (p < 0) continue;
#pragma unroll
      for (int nf = 0; nf < 4; ++nf) {
        float gg = accg[mf][nf][r], uu = accu[mf][nf][r];
        float o = (gg / (1.f + __expf(-gg))) * uu;
        act[(size_t)p * NF + f0 + wn + nf * 16 + lm] = (unsigned short)bfbits(o);
      }
    }
  }
}

// ---------------------------------------------------------------------------
// Kernel 3: down-proj MFMA GEMM, same structure. Tile 192 x 128 over H,
// K=F=1024, 512 threads. grid = (NH/128=16, MAXTILES).
// ---------------------------------------------------------------------------
__global__ __launch_bounds__(512) void phase2_mfma(
    const unsigned short* __restrict__ act, const float* __restrict__ wd,
    const int* __restrict__ tile_hdr, const int* __restrict__ entries,
    const int* __restrict__ cnt, float* __restrict__ yp) {
  const int s = blockIdx.y;
  if (s >= tile_hdr[0]) return;
  const int packed = tile_hdr[1 + s];
  const int e = packed >> 4, rt = packed & 15;
  const int n_e = cnt[e];
  const int h0 = blockIdx.x * BN;

  __shared__ unsigned short Bs[2][BN * BK];  // 2 x 16 KB
  __shared__ int pair_s[BM];

  const int tid = threadIdx.x;
  if (tid < BM) {
    int idx = rt * BM + tid;
    pair_s[tid] = (idx < n_e) ? entries[e * NT + idx] : -1;
  }
  __syncthreads();

  const int lane = tid & 63, wid = tid >> 6;
  const int wm = (wid >> 1) * 48, wn = (wid & 1) * 64;
  const int lm = lane & 15, lk = (lane >> 4) * 8;

  const unsigned short* aptr[3];
#pragma unroll
  for (int mf = 0; mf < 3; ++mf) {
    int p = pair_s[wm + mf * 16 + lm];
    int pa = (p >= 0) ? p : 0;
    aptr[mf] = act + (size_t)pa * NF + lk;
  }

  const int q = tid & 31, g4 = (tid >> 5) * 4;
  const float* bdp = wd + (size_t)e * NF * NH + h0 + q * 4;

  float rd[4][4];
  short8 a[3][2];

  f32x4 acc[3][4];
#pragma unroll
  for (int i = 0; i < 3; ++i)
#pragma unroll
    for (int j = 0; j < 4; ++j) acc[i][j] = (f32x4)(0.f);

  auto loadA = [&](int k0) {
#pragma unroll
    for (int mf = 0; mf < 3; ++mf)
#pragma unroll
      for (int kc = 0; kc < 2; ++kc)
        a[mf][kc] = *reinterpret_cast<const short8*>(aptr[mf] + k0 + kc * 32);
  };
  auto loadB = [&](int k0) {
#pragma unroll
    for (int i = 0; i < 4; ++i) {
      float4 v = *reinterpret_cast<const float4*>(bdp + (size_t)(k0 + g4 + i) * NH);
      rd[i][0] = v.x; rd[i][1] = v.y; rd[i][2] = v.z; rd[i][3] = v.w;
    }
  };
  auto storeB = [&](int b) {
#pragma unroll
    for (int j = 0; j < 4; ++j) {
      const int n = q * 4 + j;
      uint2 cd;
      cd.x = pkbf(rd[0][j], rd[1][j]); cd.y = pkbf(rd[2][j], rd[3][j]);
      *reinterpret_cast<uint2*>(&Bs[b][swz(n, g4)]) = cd;
    }
  };
  auto compute = [&](int c) {
#pragma unroll
    for (int kc = 0; kc < 2; ++kc) {
      short8 b2[4];
#pragma unroll
      for (int nf = 0; nf < 4; ++nf)
        b2[nf] = *reinterpret_cast<const short8*>(
            &Bs[c][swz(wn + nf * 16 + lm, kc * 32 + lk)]);
#pragma unroll
      for (int mf = 0; mf < 3; ++mf)
#pragma unroll
        for (int nf = 0; nf < 4; ++nf)
          acc[mf][nf] = __builtin_amdgcn_mfma_f32_16x16x32_bf16(a[mf][kc], b2[nf], acc[mf][nf], 0, 0, 0);
    }
  };

  const int NS = NF / BK;  // 16
  loadB(0);
  storeB(0);
  ASMV("s_waitcnt lgkmcnt(0)");
  __builtin_amdgcn_s_barrier();
  __builtin_amdgcn_sched_barrier(0);

  for (int t = 0; t < NS; ++t) {
    const int c = t & 1;
    loadA(t * BK);
    if (t + 1 < NS) loadB((t + 1) * BK);
    compute(c);
    if (t + 1 < NS) {
      storeB(c ^ 1);
      ASMV("s_waitcnt lgkmcnt(0)");
      __builtin_amdgcn_s_barrier();
      __builtin_amdgcn_sched_barrier(0);
    }
  }

  const int rbase = wm + (lane >> 4) * 4;
#pragma unroll
  for (int mf = 0; mf < 3; ++mf) {
#pragma unroll
    for (int r = 0; r < 4; ++r) {
      const int row = rbase + mf * 16 + r;
      const int p = pair_s[row];
      if (p < 0) continue;
#pragma unroll
      for (int nf = 0; nf < 4; ++nf)
        yp[(size_t)p * NH + h0 + wn + nf * 16 + lm] = acc[mf][nf][r];
    }
  }
}

// ---------------------------------------------------------------------------
// Kernel 4: combine (unchanged).
// ---------------------------------------------------------------------------
__global__ __launch_bounds__(256) void combine_kernel(
    const float* __restrict__ yp, const float* __restrict__ w_tk,
    float* __restrict__ out) {
  const size_t idx = (size_t)blockIdx.x * 256 + threadIdx.x;
  const int t = (int)(idx >> 9);
  const int h4 = (int)(idx & 511) * 4;
  float4 s = make_float4(0.f, 0.f, 0.f, 0.f);
#pragma unroll
  for (int k = 0; k < NK; ++k) {
    const float w = w_tk[t * NK + k];
    const float4 v = *reinterpret_cast<const float4*>(
        &yp[((size_t)(t * NK + k)) * NH + h4]);
    s.x += w * v.x; s.y += w * v.y; s.z += w * v.z; s.w += w * v.w;
  }
  *reinterpret_cast<float4*>(&out[(size_t)t * NH + h4]) = s;
}

// ---------------------------------------------------------------------------
extern "C" void kernel_launch(void* const* d_in, const int* in_sizes, int n_in,
                              void* d_out, int out_size, void* d_ws,
                              size_t ws_size, hipStream_t stream) {
  const float* x      = (const float*)d_in[0];
  const float* gate_w = (const float*)d_in[1];
  const float* wg     = (const float*)d_in[2];
  const float* wu     = (const float*)d_in[3];
  const float* wd     = (const float*)d_in[4];

  float* out        = (float*)d_out;
  float* logits_out = (float*)d_out + (size_t)NT * NH;

  char* ws = (char*)d_ws;
  int* cnt            = (int*)(ws + OFF_CNT);
  int* entries        = (int*)(ws + OFF_ENT);
  float* w_tk         = (float*)(ws + OFF_WTK);
  int* tile_hdr       = (int*)(ws + OFF_TIL);
  unsigned short* xb  = (unsigned short*)(ws + OFF_XB);
  unsigned short* act = (unsigned short*)(ws + OFF_ACT);
  float* yp           = (float*)(ws + OFF_YP);

  hipMemsetAsync(ws, 0, 1024, stream);  // zero expert counters

  router_kernel<<<NT, 256, 0, stream>>>(x, gate_w, logits_out, cnt, entries, w_tk, xb);
  build_tiles<<<1, 64, 0, stream>>>(cnt, tile_hdr);
  phase1_mfma<<<dim3(NF / BN, MAXTILES), 512, 0, stream>>>(xb, wg, wu, tile_hdr, entries, cnt, act);
  phase2_mfma<<<dim3(NH / BN, MAXTILES), 512, 0, stream>>>(act, wd, tile_hdr, entries, cnt, yp);
  combine_kernel<<<(NT * NH / 4) / 256, 256, 0, stream>>>(yp, w_tk, out);
}